// Round 10
// baseline (216.942 us; speedup 1.0000x reference)
//
#include <hip/hip_runtime.h>
#include <hip/hip_bf16.h>
#include <math.h>

// MambaBlock: 4-direction 2D selective scan + fuse + LN + SiLU
// B=2, H=W=128, D_MODEL=64, D_INNER=128, D_STATE=16, DT_RANK=4, D_CONV=4
//
// R10: (a) scan -> 1 thread/channel (tid<128), 16 states: the 2-thr/channel
// version issued dr/exp/log/rcp on all 4 waves (both lanes of a pair execute
// the same wave-inst) -> halved by running scan on 2 waves; shfl_xor + E8 seed
// deleted; decay chain split into two interleaved E^2 chains (serial depth 8).
// Freed waves park at the barrier; co-resident blocks absorb the slots (m114).
// (b) kT2 deleted: k0's transpose blocks write both XH and XW layouts.
//
//  K0: fold out_w*fuse_w -> MT16; in_w/xp_w -> bf16; x -> xhwc16 + xwhc16.
//  K1 (53,248B LDS, 3 blk/CU): MFMA in-proj (B from global) -> conv4+silu ->
//      MFMA xp-proj (to LDS) -> scan (1 thr/channel) -> z-mul from regs -> YF.
//  K3 (66,560B LDS, 2 blk/CU): contiguous gather, MFMA vs MT16, LN, SiLU.

typedef __attribute__((ext_vector_type(8))) short short8;
typedef __attribute__((ext_vector_type(4))) float f32x4;

__device__ __forceinline__ unsigned int pk2bf(float a, float b) {
  __hip_bfloat162 h = __float22bfloat162_rn(make_float2(a, b));
  unsigned int u;
  __builtin_memcpy(&u, &h, 4);
  return u;
}
__device__ __forceinline__ unsigned short f2bf(float f) {
  __hip_bfloat16 h = __float2bfloat16(f);
  unsigned short s;
  __builtin_memcpy(&s, &h, 2);
  return s;
}
__device__ __forceinline__ float bf2f(unsigned short h) {
  return __uint_as_float(((unsigned int)h) << 16);
}
__device__ __forceinline__ float fastrcp(float x) { return __builtin_amdgcn_rcpf(x); }
__device__ __forceinline__ float siluf(float x) { return x * fastrcp(1.f + __expf(-x)); }

// ---------------------------------------------------------------- K0
// blk 0..127: fold -> MT16. 128..159: in_w -> W16. 160..163: xp_w -> XW16.
// blk 164..419: x[b][c][h][w] -> xhwc16[b][h][w][c] AND xwhc16[b][w][h][c].
__global__ void k0_prep(const float* __restrict__ out_w, const float* __restrict__ fuse_w,
                        const float* __restrict__ in_w, const float* __restrict__ xp_w,
                        const float* __restrict__ x,
                        unsigned short* __restrict__ MT16, unsigned short* __restrict__ W16,
                        unsigned short* __restrict__ XW16, unsigned short* __restrict__ XH,
                        unsigned short* __restrict__ XW) {
  __shared__ unsigned short sT[64*132];   // transpose stage (blk>=164 only)
  int blk = blockIdx.x;
  int tid = threadIdx.x;
  if (blk < 128) {
    int idx = blk * 256 + tid;   // 32768
    int d   = idx & 127;
    int o   = (idx >> 7) & 63;
    int dir = idx >> 13;
    float acc = 0.f;
    #pragma unroll 8
    for (int j = 0; j < 64; ++j)
      acc += out_w[(dir*64 + j)*128 + d] * fuse_w[o*256 + dir*64 + j];
    MT16[o*512 + dir*128 + d] = f2bf(acc);   // M^T layout [o][j=dir*128+d]
  } else if (blk < 160) {
    int t = (blk - 128) * 256 + tid;
    int base = t * 8;                        // 65536 total
    float4 v0 = *(const float4*)(in_w + base);
    float4 v1 = *(const float4*)(in_w + base + 4);
    uint4 pk;
    pk.x = pk2bf(v0.x, v0.y);
    pk.y = pk2bf(v0.z, v0.w);
    pk.z = pk2bf(v1.x, v1.y);
    pk.w = pk2bf(v1.z, v1.w);
    *(uint4*)(W16 + base) = pk;
  } else if (blk < 164) {
    int t = (blk - 160) * 256 + tid;        // 1024 threads
    for (int pid = t; pid < 4*48*128; pid += 1024) {
      int dir = pid / 6144;
      int rem = pid - dir*6144;
      int row = rem >> 7, c = rem & 127;
      XW16[pid] = (row < 36) ? f2bf(xp_w[dir*4608 + row*128 + c]) : (unsigned short)0;
    }
  } else {
    int idx = blk - 164;                    // 0..255
    int b = idx >> 7, h = idx & 127;
    for (int f = tid*4; f < 8192; f += 1024) {
      int c = f >> 7, w = f & 127;
      float4 v = *(const float4*)(x + (((size_t)(b*64 + c)*128 + h)*128 + w));
      sT[c*132 + w + 0] = f2bf(v.x);
      sT[c*132 + w + 1] = f2bf(v.y);
      sT[c*132 + w + 2] = f2bf(v.z);
      sT[c*132 + w + 3] = f2bf(v.w);
    }
    __syncthreads();
    for (int f = tid*8; f < 8192; f += 2048) {
      int w = f >> 6, c0 = f & 63;
      unsigned int pk[4];
      #pragma unroll
      for (int p = 0; p < 4; ++p) {
        unsigned int lo = sT[(c0 + p*2 + 0)*132 + w];
        unsigned int hi = sT[(c0 + p*2 + 1)*132 + w];
        pk[p] = lo | (hi << 16);
      }
      uint4 v; v.x = pk[0]; v.y = pk[1]; v.z = pk[2]; v.w = pk[3];
      *(uint4*)(XH + (((size_t)(b*128 + h)*128 + w)*64 + c0)) = v;
      *(uint4*)(XW + (((size_t)(b*128 + w)*128 + h)*64 + c0)) = v;
    }
  }
}

// ---------------------------------------------------------------- K1 (fused)
// LDS (53,248 B -> 3 blocks/CU):
//   sBCf @0     18432B fp32 [128 tok][36] (B cols 0..15, C cols 16..31) [ph4+]
//   sUC  @18432 34816B bf16 [128 tok][136]; cols 0..127 = u_pre -> uc -> y;
//                      cols 128..135 = dt-rank float4 [ph4+]
__global__ __launch_bounds__(256, 3) void k1_front(
    const unsigned short* __restrict__ XH, const unsigned short* __restrict__ XW,
    const unsigned short* __restrict__ W16, const unsigned short* __restrict__ XW16,
    const float* __restrict__ conv_w, const float* __restrict__ conv_b,
    const float* __restrict__ dtp_w, const float* __restrict__ dtp_b,
    const float* __restrict__ A_log, const float* __restrict__ Dp,
    unsigned short* __restrict__ YF)
{
  __shared__ __align__(16) char smem[53248];
  float* sBCf         = (float*)smem;                      // [128][36]  (ph4+)
  unsigned short* sUC = (unsigned short*)(smem + 18432);   // [128][136]

  const int tid = threadIdx.x;
  const int dir = blockIdx.x >> 8;
  const int n   = blockIdx.x & 255;
  const int b   = n >> 7;
  const int r   = n & 127;
  const int n_all = dir*256 + n;

  const unsigned short* xsrc = (dir < 2 ? XH : XW) + ((size_t)(b*128 + r)*128)*64;

  const int wave = tid >> 6;
  const int lane = tid & 63;
  const int m16 = lane & 15;
  const int quad = lane >> 4;
  const int tb0 = wave * 32;
  const int st0 = tb0 + m16;          // scan-order tokens owned (B-fragment rows)
  const int st1 = tb0 + 16 + m16;
  const int sp0 = (dir & 1) ? (127 - st0) : st0;   // spatial index in xsrc
  const int sp1 = (dir & 1) ? (127 - st1) : st1;

  unsigned int zpk[2][8][2];   // silu(z) bf16-packed: [tok-half][k][pair] (32 VGPRs)

  // ---- phase 2: MFMA in-projection. A=in_w (global bf16), B=x (global bf16). ----
  {
    short8 bfr[2][2];
    #pragma unroll
    for (int ks = 0; ks < 2; ++ks) {
      bfr[0][ks] = *(const short8*)(xsrc + sp0*64 + ks*32 + quad*8);
      bfr[1][ks] = *(const short8*)(xsrc + sp1*64 + ks*32 + quad*8);
    }
    const unsigned short* Wd = W16 + (size_t)dir * 16384;

    // u rows (rt 0..7)
    for (int rt = 0; rt < 8; ++rt) {
      short8 af[2];
      #pragma unroll
      for (int ks = 0; ks < 2; ++ks)
        af[ks] = *(const short8*)(Wd + (rt*16 + m16)*64 + ks*32 + quad*8);
      #pragma unroll
      for (int tt = 0; tt < 2; ++tt) {
        f32x4 acc = {0.f, 0.f, 0.f, 0.f};
        acc = __builtin_amdgcn_mfma_f32_16x16x32_bf16(af[0], bfr[tt][0], acc, 0, 0, 0);
        acc = __builtin_amdgcn_mfma_f32_16x16x32_bf16(af[1], bfr[tt][1], acc, 0, 0, 0);
        const int tok = tt ? st1 : st0;
        const int r0 = rt*16 + quad*4;
        uint2 u2;
        u2.x = pk2bf(acc[0], acc[1]);
        u2.y = pk2bf(acc[2], acc[3]);
        *(uint2*)(sUC + tok*136 + r0) = u2;
      }
    }
    // z rows (rt 8..15) -> registers
    #pragma unroll
    for (int k = 0; k < 8; ++k) {
      short8 af[2];
      #pragma unroll
      for (int ks = 0; ks < 2; ++ks)
        af[ks] = *(const short8*)(Wd + ((8+k)*16 + m16)*64 + ks*32 + quad*8);
      #pragma unroll
      for (int tt = 0; tt < 2; ++tt) {
        f32x4 acc = {0.f, 0.f, 0.f, 0.f};
        acc = __builtin_amdgcn_mfma_f32_16x16x32_bf16(af[0], bfr[tt][0], acc, 0, 0, 0);
        acc = __builtin_amdgcn_mfma_f32_16x16x32_bf16(af[1], bfr[tt][1], acc, 0, 0, 0);
        zpk[tt][k][0] = pk2bf(siluf(acc[0]), siluf(acc[1]));
        zpk[tt][k][1] = pk2bf(siluf(acc[2]), siluf(acc[3]));
      }
    }
  }
  __syncthreads();

  // ---- phase 3: causal conv-4 + silu in sUC (bf16). 4 chunks of 32 tokens;
  //      each thread interleaves 2 independent chunks for ILP on the serial chain.
  {
    const int d = tid & 127;
    const int half = tid >> 7;
    const int ca = half * 32;          // chunk A: 0 or 32
    const int cb2 = (half + 2) * 32;   // chunk B: 64 or 96
    const float* cw = conv_w + (size_t)(dir*128 + d)*4;
    const float c0w = cw[0], c1w = cw[1], c2w = cw[2], c3w = cw[3];
    const float cbv = conv_b[dir*128 + d];
    float a0 = half ? bf2f(sUC[(ca-3)*136 + d]) : 0.f;
    float a1 = half ? bf2f(sUC[(ca-2)*136 + d]) : 0.f;
    float a2 = half ? bf2f(sUC[(ca-1)*136 + d]) : 0.f;
    float b0 = bf2f(sUC[(cb2-3)*136 + d]);
    float b1 = bf2f(sUC[(cb2-2)*136 + d]);
    float b2 = bf2f(sUC[(cb2-1)*136 + d]);
    __syncthreads();
    for (int i = 0; i < 32; ++i) {
      float curA = bf2f(sUC[(ca+i)*136 + d]);
      float curB = bf2f(sUC[(cb2+i)*136 + d]);
      float vA = cbv + c0w*a0 + c1w*a1 + c2w*a2 + c3w*curA;
      float vB = cbv + c0w*b0 + c1w*b1 + c2w*b2 + c3w*curB;
      sUC[(ca+i)*136 + d]  = f2bf(siluf(vA));
      sUC[(cb2+i)*136 + d] = f2bf(siluf(vB));
      a0 = a1; a1 = a2; a2 = curA;
      b0 = b1; b1 = b2; b2 = curB;
    }
  }
  __syncthreads();

  // ---- phase 4: MFMA xp-projection. A=xp_w (global bf16), B=uc (LDS sUC).
  //      dt rows -> sUC cols 128..135 (float4); B/C rows -> sBCf (fp32).
  {
    short8 bfr[2][4];
    #pragma unroll
    for (int tt = 0; tt < 2; ++tt)
      #pragma unroll
      for (int ks = 0; ks < 4; ++ks)
        bfr[tt][ks] = *(const short8*)(sUC + (tt ? st1 : st0)*136 + ks*32 + quad*8);

    const unsigned short* XWd = XW16 + (size_t)dir * (48*128);

    for (int rt = 0; rt < 3; ++rt) {
      short8 af[4];
      #pragma unroll
      for (int ks = 0; ks < 4; ++ks)
        af[ks] = *(const short8*)(XWd + (rt*16 + m16)*128 + ks*32 + quad*8);
      #pragma unroll
      for (int tt = 0; tt < 2; ++tt) {
        f32x4 acc = {0.f, 0.f, 0.f, 0.f};
        #pragma unroll
        for (int ks = 0; ks < 4; ++ks)
          acc = __builtin_amdgcn_mfma_f32_16x16x32_bf16(af[ks], bfr[tt][ks], acc, 0, 0, 0);
        const int tok = tt ? st1 : st0;
        const int r0 = rt*16 + quad*4;   // 0,4,...,44
        if (r0 == 0) {
          float4 v; v.x = acc[0]; v.y = acc[1]; v.z = acc[2]; v.w = acc[3];
          *(float4*)(smem + 18432 + tok*272 + 256) = v;      // sUC cols 128..135
        } else if (r0 < 36) {
          float4 v; v.x = acc[0]; v.y = acc[1]; v.z = acc[2]; v.w = acc[3];
          *(float4*)(sBCf + tok*36 + (r0 - 4)) = v;          // B: 0..15, C: 16..31
        }
      }
    }
  }
  __syncthreads();

  // ---- phase 5: selective scan, 1 thread/channel (16 states); waves 2,3 idle.
  if (tid < 128) {
    const int d = tid;
    const float* dwp = dtp_w + (size_t)(dir*128 + d) * 4;
    const float dw0 = dwp[0], dw1 = dwp[1], dw2 = dwp[2], dw3 = dwp[3];
    const float db = dtp_b[dir*128 + d];
    const float dpv = Dp[dir*128 + d];

    float Av[16];
    bool fast = true;
    #pragma unroll
    for (int j = 0; j < 16; ++j) {
      float a = -__expf(A_log[((size_t)(dir*128 + d))*16 + j]);
      Av[j] = a;
      if (fabsf((-a) - (float)(j + 1)) > 1e-3f) fast = false;
    }

    float h[16];
    #pragma unroll
    for (int j = 0; j < 16; ++j) h[j] = 0.f;

    #define SCAN_LOAD                                                     \
      float4 q0 = *(const float4*)(smem + 18432 + l*272 + 256);           \
      float4 b0 = *(const float4*)(sBCf + l*36);                          \
      float4 b1 = *(const float4*)(sBCf + l*36 + 4);                      \
      float4 b2 = *(const float4*)(sBCf + l*36 + 8);                      \
      float4 b3 = *(const float4*)(sBCf + l*36 + 12);                     \
      float4 c0 = *(const float4*)(sBCf + l*36 + 16);                     \
      float4 c1 = *(const float4*)(sBCf + l*36 + 20);                     \
      float4 c2 = *(const float4*)(sBCf + l*36 + 24);                     \
      float4 c3 = *(const float4*)(sBCf + l*36 + 28);                     \
      float Bv[16] = {b0.x,b0.y,b0.z,b0.w, b1.x,b1.y,b1.z,b1.w,           \
                      b2.x,b2.y,b2.z,b2.w, b3.x,b3.y,b3.z,b3.w};          \
      float Cv[16] = {c0.x,c0.y,c0.z,c0.w, c1.x,c1.y,c1.z,c1.w,           \
                      c2.x,c2.y,c2.z,c2.w, c3.x,c3.y,c3.z,c3.w};          \
      float dr = q0.x*dw0 + q0.y*dw1 + q0.z*dw2 + q0.w*dw3 + db;          \
      float te = __expf(dr);                                              \
      float dt = (dr > 20.f) ? dr : __logf(1.f + te);                     \
      float u = bf2f(sUC[l*136 + d]);                                     \
      float dtu = dt * u;

    if (fast) {
      for (int l = 0; l < 128; ++l) {
        SCAN_LOAD
        float E = fastrcp(1.f + te);   // exp(-softplus(dr))
        float E2 = E*E;
        float ea = E, eb = E2;         // two chains: E^1,E^3,.. / E^2,E^4,..
        float yp = 0.f;
        #pragma unroll
        for (int j = 0; j < 16; j += 2) {
          h[j]   = h[j]*ea   + dtu*Bv[j];   yp += h[j]*Cv[j];
          h[j+1] = h[j+1]*eb + dtu*Bv[j+1]; yp += h[j+1]*Cv[j+1];
          ea *= E2; eb *= E2;
        }
        sUC[l*136 + d] = f2bf(yp + u*dpv);
      }
    } else {
      for (int l = 0; l < 128; ++l) {
        SCAN_LOAD
        float yp = 0.f;
        #pragma unroll
        for (int j = 0; j < 16; ++j) {
          float ej = __expf(dt*Av[j]);
          h[j] = h[j]*ej + dtu*Bv[j];
          yp += h[j]*Cv[j];
        }
        sUC[l*136 + d] = f2bf(yp + u*dpv);
      }
    }
    #undef SCAN_LOAD
  }
  __syncthreads();

  // ---- phase 6: yf = y * silu(z) from registers; dir-dependent YF layout.
  //      dir 0/1: [n_all][l][d]; dir 2/3: transposed [dir][b*128+h][w][d].
  #pragma unroll
  for (int tt = 0; tt < 2; ++tt) {
    const int st = tt ? st1 : st0;
    size_t rowbase;
    if (dir < 2)       rowbase = ((size_t)n_all*128 + st)*128;
    else if (dir == 2) rowbase = ((size_t)(512 + b*128 + st)*128 + r)*128;
    else               rowbase = ((size_t)(768 + b*128 + (127-st))*128 + r)*128;
    #pragma unroll
    for (int k = 0; k < 8; ++k) {
      const int dz = 16*k + quad*4;
      uint2 yv = *(const uint2*)(sUC + st*136 + dz);
      float y0 = __uint_as_float(yv.x << 16);
      float y1 = __uint_as_float(yv.x & 0xffff0000u);
      float y2 = __uint_as_float(yv.y << 16);
      float y3 = __uint_as_float(yv.y & 0xffff0000u);
      unsigned int z01 = zpk[tt][k][0], z23 = zpk[tt][k][1];
      float z0 = __uint_as_float(z01 << 16);
      float z1 = __uint_as_float(z01 & 0xffff0000u);
      float z2 = __uint_as_float(z23 << 16);
      float z3 = __uint_as_float(z23 & 0xffff0000u);
      uint2 ov;
      ov.x = pk2bf(y0*z0, y1*z1);
      ov.y = pk2bf(y2*z2, y3*z3);
      *(uint2*)(YF + rowbase + dz) = ov;
    }
  }
}

// ---------------------------------------------------------------- K3 (MFMA fuse + LN)
__global__ __launch_bounds__(256, 2) void k3_fuse(
    const unsigned short* __restrict__ YF, const unsigned short* __restrict__ MT16,
    const float* __restrict__ fuse_b, const float* __restrict__ ln_g,
    const float* __restrict__ ln_b, float* __restrict__ out)
{
  __shared__ __align__(16) unsigned short sYB[64*520];   // 66,560 B

  const int tid = threadIdx.x;
  const int blk = blockIdx.x;             // 512
  const int b = blk >> 8;
  const int rr2 = blk & 255;
  const int h = rr2 >> 1;
  const int w0 = (rr2 & 1) * 64;

  for (int f = tid*8; f < 32768; f += 2048) {
    int dirg = f >> 13;
    int rem = f & 8191;
    int tok = rem >> 7;
    int dd = rem & 127;
    int X = (dirg == 1) ? (127 - w0 - tok) : (w0 + tok);
    size_t base = ((size_t)(dirg*256 + b*128 + h)*128 + X)*128 + dd;
    *(uint4*)(sYB + tok*520 + dirg*128 + dd) = *(const uint4*)(YF + base);
  }
  __syncthreads();

  const int wave = tid >> 6;
  const int lane = tid & 63;
  const int m16 = lane & 15;
  const int quad = lane >> 4;
  const int tok = wave*16 + m16;

  short8 bfr[16];
  #pragma unroll
  for (int jt = 0; jt < 16; ++jt)
    bfr[jt] = *(const short8*)(sYB + tok*520 + jt*32 + quad*8);

  float facc[4][4];
  #pragma unroll
  for (int mt = 0; mt < 4; ++mt) {
    f32x4 acc = {0.f, 0.f, 0.f, 0.f};
    #pragma unroll
    for (int jt = 0; jt < 16; ++jt) {
      short8 af = *(const short8*)(MT16 + (size_t)(mt*16 + m16)*512 + jt*32 + quad*8);
      acc = __builtin_amdgcn_mfma_f32_16x16x32_bf16(af, bfr[jt], acc, 0, 0, 0);
    }
    facc[mt][0] = acc[0]; facc[mt][1] = acc[1]; facc[mt][2] = acc[2]; facc[mt][3] = acc[3];
  }

  float fv[16];
  float s1 = 0.f, s2 = 0.f;
  #pragma unroll
  for (int mt = 0; mt < 4; ++mt)
    #pragma unroll
    for (int rr = 0; rr < 4; ++rr) {
      int o = mt*16 + quad*4 + rr;
      float v = facc[mt][rr] + fuse_b[o];
      fv[mt*4 + rr] = v;
      s1 += v; s2 += v*v;
    }
  s1 += __shfl_xor(s1, 16, 64); s1 += __shfl_xor(s1, 32, 64);
  s2 += __shfl_xor(s2, 16, 64); s2 += __shfl_xor(s2, 32, 64);
  float mu = s1 * (1.f/64.f);
  float var = s2 * (1.f/64.f) - mu*mu;
  float rs = rsqrtf(var + 1e-5f);

  #pragma unroll
  for (int mt = 0; mt < 4; ++mt)
    #pragma unroll
    for (int rr = 0; rr < 4; ++rr) {
      int o = mt*16 + quad*4 + rr;
      float v = (fv[mt*4 + rr] - mu) * rs * ln_g[o] + ln_b[o];
      out[((size_t)(b*64 + o)*128 + h)*128 + (w0 + tok)] = siluf(v);
    }
}

// ---------------------------------------------------------------- host
extern "C" void kernel_launch(void* const* d_in, const int* in_sizes, int n_in,
                              void* d_out, int out_size, void* d_ws, size_t ws_size,
                              hipStream_t stream) {
  const float* x      = (const float*)d_in[0];
  const float* in_w   = (const float*)d_in[1];
  const float* conv_w = (const float*)d_in[2];
  const float* conv_b = (const float*)d_in[3];
  const float* xp_w   = (const float*)d_in[4];
  const float* dtp_w  = (const float*)d_in[5];
  const float* dtp_b  = (const float*)d_in[6];
  const float* A_log  = (const float*)d_in[7];
  const float* Dp     = (const float*)d_in[8];
  const float* out_w  = (const float*)d_in[9];
  const float* fuse_w = (const float*)d_in[10];
  const float* fuse_b = (const float*)d_in[11];
  const float* ln_g   = (const float*)d_in[12];
  const float* ln_b   = (const float*)d_in[13];
  float* out = (float*)d_out;

  // ws layout (BYTES):
  char* ws = (char*)d_ws;
  unsigned short* YF   = (unsigned short*)(ws);              // 33,554,432 (yf, dir-layouts)
  unsigned short* MT16 = (unsigned short*)(ws + 33554432);   //     65,536
  unsigned short* W16  = (unsigned short*)(ws + 33619968);   //    131,072
  unsigned short* XW16 = (unsigned short*)(ws + 33751040);   //     49,152
  unsigned short* XH   = (unsigned short*)(ws + 33800192);   //  4,194,304 (xhwc16)
  unsigned short* XWt  = (unsigned short*)(ws + 37994496);   //  4,194,304 (xwhc16)
  // total 42,188,800 B

  k0_prep<<<dim3(420), dim3(256), 0, stream>>>(out_w, fuse_w, in_w, xp_w, x,
                                               MT16, W16, XW16, XH, XWt);
  k1_front<<<dim3(1024), dim3(256), 0, stream>>>(XH, XWt, W16, XW16, conv_w, conv_b,
                                                 dtp_w, dtp_b, A_log, Dp, YF);
  k3_fuse<<<dim3(512), dim3(256), 0, stream>>>(YF, MT16, fuse_b, ln_g, ln_b, out);
}

// Round 11
// 208.839 us; speedup vs baseline: 1.0388x; 1.0388x over previous
//
#include <hip/hip_runtime.h>
#include <hip/hip_bf16.h>
#include <math.h>

// MambaBlock: 4-direction 2D selective scan + fuse + LN + SiLU
// B=2, H=W=128, D_MODEL=64, D_INNER=128, D_STATE=16, DT_RANK=4, D_CONV=4
//
// R11 = best-of recombination. R10 taught: scan is LATENCY-bound, not
// issue-bound -- 1 thr/channel halved issue capacity and doubled serial depth
// (VALUBusy 65->44, k1 106.7->115.5). Revert scan to R9's 2 thr/channel
// (redundant pair-uniform transcendentals are cheaper than halved TLP).
// Keep R10's kT2-fold into k0 (residual dropped 106.9->101.4us).
//
//  K0: fold out_w*fuse_w -> MT16; in_w/xp_w -> bf16; x -> xhwc16 AND xwhc16.
//  K1 (53,248B LDS, 3 blk/CU): MFMA in-proj (B from global) -> conv4+silu ->
//      MFMA xp-proj (to LDS) -> scan (2 thr/channel, fp32 B/C) -> z-mul from
//      regs -> YF (dir-dependent layout).
//  K3 (66,560B LDS, 2 blk/CU): contiguous gather, MFMA vs MT16, LN, SiLU.

typedef __attribute__((ext_vector_type(8))) short short8;
typedef __attribute__((ext_vector_type(4))) float f32x4;

__device__ __forceinline__ unsigned int pk2bf(float a, float b) {
  __hip_bfloat162 h = __float22bfloat162_rn(make_float2(a, b));
  unsigned int u;
  __builtin_memcpy(&u, &h, 4);
  return u;
}
__device__ __forceinline__ unsigned short f2bf(float f) {
  __hip_bfloat16 h = __float2bfloat16(f);
  unsigned short s;
  __builtin_memcpy(&s, &h, 2);
  return s;
}
__device__ __forceinline__ float bf2f(unsigned short h) {
  return __uint_as_float(((unsigned int)h) << 16);
}
__device__ __forceinline__ float fastrcp(float x) { return __builtin_amdgcn_rcpf(x); }
__device__ __forceinline__ float siluf(float x) { return x * fastrcp(1.f + __expf(-x)); }

// ---------------------------------------------------------------- K0
// blk 0..127: fold -> MT16. 128..159: in_w -> W16. 160..163: xp_w -> XW16.
// blk 164..419: x[b][c][h][w] -> xhwc16[b][h][w][c] AND xwhc16[b][w][h][c].
__global__ void k0_prep(const float* __restrict__ out_w, const float* __restrict__ fuse_w,
                        const float* __restrict__ in_w, const float* __restrict__ xp_w,
                        const float* __restrict__ x,
                        unsigned short* __restrict__ MT16, unsigned short* __restrict__ W16,
                        unsigned short* __restrict__ XW16, unsigned short* __restrict__ XH,
                        unsigned short* __restrict__ XW) {
  __shared__ unsigned short sT[64*132];   // transpose stage (blk>=164 only)
  int blk = blockIdx.x;
  int tid = threadIdx.x;
  if (blk < 128) {
    int idx = blk * 256 + tid;   // 32768
    int d   = idx & 127;
    int o   = (idx >> 7) & 63;
    int dir = idx >> 13;
    float acc = 0.f;
    #pragma unroll 8
    for (int j = 0; j < 64; ++j)
      acc += out_w[(dir*64 + j)*128 + d] * fuse_w[o*256 + dir*64 + j];
    MT16[o*512 + dir*128 + d] = f2bf(acc);   // M^T layout [o][j=dir*128+d]
  } else if (blk < 160) {
    int t = (blk - 128) * 256 + tid;
    int base = t * 8;                        // 65536 total
    float4 v0 = *(const float4*)(in_w + base);
    float4 v1 = *(const float4*)(in_w + base + 4);
    uint4 pk;
    pk.x = pk2bf(v0.x, v0.y);
    pk.y = pk2bf(v0.z, v0.w);
    pk.z = pk2bf(v1.x, v1.y);
    pk.w = pk2bf(v1.z, v1.w);
    *(uint4*)(W16 + base) = pk;
  } else if (blk < 164) {
    int t = (blk - 160) * 256 + tid;        // 1024 threads
    for (int pid = t; pid < 4*48*128; pid += 1024) {
      int dir = pid / 6144;
      int rem = pid - dir*6144;
      int row = rem >> 7, c = rem & 127;
      XW16[pid] = (row < 36) ? f2bf(xp_w[dir*4608 + row*128 + c]) : (unsigned short)0;
    }
  } else {
    int idx = blk - 164;                    // 0..255
    int b = idx >> 7, h = idx & 127;
    for (int f = tid*4; f < 8192; f += 1024) {
      int c = f >> 7, w = f & 127;
      float4 v = *(const float4*)(x + (((size_t)(b*64 + c)*128 + h)*128 + w));
      sT[c*132 + w + 0] = f2bf(v.x);
      sT[c*132 + w + 1] = f2bf(v.y);
      sT[c*132 + w + 2] = f2bf(v.z);
      sT[c*132 + w + 3] = f2bf(v.w);
    }
    __syncthreads();
    for (int f = tid*8; f < 8192; f += 2048) {
      int w = f >> 6, c0 = f & 63;
      unsigned int pk[4];
      #pragma unroll
      for (int p = 0; p < 4; ++p) {
        unsigned int lo = sT[(c0 + p*2 + 0)*132 + w];
        unsigned int hi = sT[(c0 + p*2 + 1)*132 + w];
        pk[p] = lo | (hi << 16);
      }
      uint4 v; v.x = pk[0]; v.y = pk[1]; v.z = pk[2]; v.w = pk[3];
      *(uint4*)(XH + (((size_t)(b*128 + h)*128 + w)*64 + c0)) = v;
      *(uint4*)(XW + (((size_t)(b*128 + w)*128 + h)*64 + c0)) = v;
    }
  }
}

// ---------------------------------------------------------------- K1 (fused)
// LDS (53,248 B -> 3 blocks/CU):
//   sBCf @0     18432B fp32 [128 tok][36] (B cols 0..15, C cols 16..31) [ph4+]
//   sUC  @18432 34816B bf16 [128 tok][136]; cols 0..127 = u_pre -> uc -> y;
//                      cols 128..135 = dt-rank float4 [ph4+]
__global__ __launch_bounds__(256, 3) void k1_front(
    const unsigned short* __restrict__ XH, const unsigned short* __restrict__ XW,
    const unsigned short* __restrict__ W16, const unsigned short* __restrict__ XW16,
    const float* __restrict__ conv_w, const float* __restrict__ conv_b,
    const float* __restrict__ dtp_w, const float* __restrict__ dtp_b,
    const float* __restrict__ A_log, const float* __restrict__ Dp,
    unsigned short* __restrict__ YF)
{
  __shared__ __align__(16) char smem[53248];
  float* sBCf         = (float*)smem;                      // [128][36]  (ph4+)
  unsigned short* sUC = (unsigned short*)(smem + 18432);   // [128][136]

  const int tid = threadIdx.x;
  const int dir = blockIdx.x >> 8;
  const int n   = blockIdx.x & 255;
  const int b   = n >> 7;
  const int r   = n & 127;
  const int n_all = dir*256 + n;

  const unsigned short* xsrc = (dir < 2 ? XH : XW) + ((size_t)(b*128 + r)*128)*64;

  const int wave = tid >> 6;
  const int lane = tid & 63;
  const int m16 = lane & 15;
  const int quad = lane >> 4;
  const int tb0 = wave * 32;
  const int st0 = tb0 + m16;          // scan-order tokens owned (B-fragment rows)
  const int st1 = tb0 + 16 + m16;
  const int sp0 = (dir & 1) ? (127 - st0) : st0;   // spatial index in xsrc
  const int sp1 = (dir & 1) ? (127 - st1) : st1;

  unsigned int zpk[2][8][2];   // silu(z) bf16-packed: [tok-half][k][pair] (32 VGPRs)

  // ---- phase 2: MFMA in-projection. A=in_w (global bf16), B=x (global bf16). ----
  {
    short8 bfr[2][2];
    #pragma unroll
    for (int ks = 0; ks < 2; ++ks) {
      bfr[0][ks] = *(const short8*)(xsrc + sp0*64 + ks*32 + quad*8);
      bfr[1][ks] = *(const short8*)(xsrc + sp1*64 + ks*32 + quad*8);
    }
    const unsigned short* Wd = W16 + (size_t)dir * 16384;

    // u rows (rt 0..7)
    for (int rt = 0; rt < 8; ++rt) {
      short8 af[2];
      #pragma unroll
      for (int ks = 0; ks < 2; ++ks)
        af[ks] = *(const short8*)(Wd + (rt*16 + m16)*64 + ks*32 + quad*8);
      #pragma unroll
      for (int tt = 0; tt < 2; ++tt) {
        f32x4 acc = {0.f, 0.f, 0.f, 0.f};
        acc = __builtin_amdgcn_mfma_f32_16x16x32_bf16(af[0], bfr[tt][0], acc, 0, 0, 0);
        acc = __builtin_amdgcn_mfma_f32_16x16x32_bf16(af[1], bfr[tt][1], acc, 0, 0, 0);
        const int tok = tt ? st1 : st0;
        const int r0 = rt*16 + quad*4;
        uint2 u2;
        u2.x = pk2bf(acc[0], acc[1]);
        u2.y = pk2bf(acc[2], acc[3]);
        *(uint2*)(sUC + tok*136 + r0) = u2;
      }
    }
    // z rows (rt 8..15) -> registers
    #pragma unroll
    for (int k = 0; k < 8; ++k) {
      short8 af[2];
      #pragma unroll
      for (int ks = 0; ks < 2; ++ks)
        af[ks] = *(const short8*)(Wd + ((8+k)*16 + m16)*64 + ks*32 + quad*8);
      #pragma unroll
      for (int tt = 0; tt < 2; ++tt) {
        f32x4 acc = {0.f, 0.f, 0.f, 0.f};
        acc = __builtin_amdgcn_mfma_f32_16x16x32_bf16(af[0], bfr[tt][0], acc, 0, 0, 0);
        acc = __builtin_amdgcn_mfma_f32_16x16x32_bf16(af[1], bfr[tt][1], acc, 0, 0, 0);
        zpk[tt][k][0] = pk2bf(siluf(acc[0]), siluf(acc[1]));
        zpk[tt][k][1] = pk2bf(siluf(acc[2]), siluf(acc[3]));
      }
    }
  }
  __syncthreads();

  // ---- phase 3: causal conv-4 + silu in sUC (bf16). 4 chunks of 32 tokens;
  //      each thread interleaves 2 independent chunks for ILP on the serial chain.
  {
    const int d = tid & 127;
    const int half = tid >> 7;
    const int ca = half * 32;          // chunk A: 0 or 32
    const int cb2 = (half + 2) * 32;   // chunk B: 64 or 96
    const float* cw = conv_w + (size_t)(dir*128 + d)*4;
    const float c0w = cw[0], c1w = cw[1], c2w = cw[2], c3w = cw[3];
    const float cbv = conv_b[dir*128 + d];
    float a0 = half ? bf2f(sUC[(ca-3)*136 + d]) : 0.f;
    float a1 = half ? bf2f(sUC[(ca-2)*136 + d]) : 0.f;
    float a2 = half ? bf2f(sUC[(ca-1)*136 + d]) : 0.f;
    float b0 = bf2f(sUC[(cb2-3)*136 + d]);
    float b1 = bf2f(sUC[(cb2-2)*136 + d]);
    float b2 = bf2f(sUC[(cb2-1)*136 + d]);
    __syncthreads();
    for (int i = 0; i < 32; ++i) {
      float curA = bf2f(sUC[(ca+i)*136 + d]);
      float curB = bf2f(sUC[(cb2+i)*136 + d]);
      float vA = cbv + c0w*a0 + c1w*a1 + c2w*a2 + c3w*curA;
      float vB = cbv + c0w*b0 + c1w*b1 + c2w*b2 + c3w*curB;
      sUC[(ca+i)*136 + d]  = f2bf(siluf(vA));
      sUC[(cb2+i)*136 + d] = f2bf(siluf(vB));
      a0 = a1; a1 = a2; a2 = curA;
      b0 = b1; b1 = b2; b2 = curB;
    }
  }
  __syncthreads();

  // ---- phase 4: MFMA xp-projection. A=xp_w (global bf16), B=uc (LDS sUC).
  //      dt rows -> sUC cols 128..135 (float4); B/C rows -> sBCf (fp32).
  {
    short8 bfr[2][4];
    #pragma unroll
    for (int tt = 0; tt < 2; ++tt)
      #pragma unroll
      for (int ks = 0; ks < 4; ++ks)
        bfr[tt][ks] = *(const short8*)(sUC + (tt ? st1 : st0)*136 + ks*32 + quad*8);

    const unsigned short* XWd = XW16 + (size_t)dir * (48*128);

    for (int rt = 0; rt < 3; ++rt) {
      short8 af[4];
      #pragma unroll
      for (int ks = 0; ks < 4; ++ks)
        af[ks] = *(const short8*)(XWd + (rt*16 + m16)*128 + ks*32 + quad*8);
      #pragma unroll
      for (int tt = 0; tt < 2; ++tt) {
        f32x4 acc = {0.f, 0.f, 0.f, 0.f};
        #pragma unroll
        for (int ks = 0; ks < 4; ++ks)
          acc = __builtin_amdgcn_mfma_f32_16x16x32_bf16(af[ks], bfr[tt][ks], acc, 0, 0, 0);
        const int tok = tt ? st1 : st0;
        const int r0 = rt*16 + quad*4;   // 0,4,...,44
        if (r0 == 0) {
          float4 v; v.x = acc[0]; v.y = acc[1]; v.z = acc[2]; v.w = acc[3];
          *(float4*)(smem + 18432 + tok*272 + 256) = v;      // sUC cols 128..135
        } else if (r0 < 36) {
          float4 v; v.x = acc[0]; v.y = acc[1]; v.z = acc[2]; v.w = acc[3];
          *(float4*)(sBCf + tok*36 + (r0 - 4)) = v;          // B: 0..15, C: 16..31
        }
      }
    }
  }
  __syncthreads();

  // ---- phase 5: selective scan, 2 threads/channel (8 states each). ----
  //      (R10 lesson: scan is latency-bound; keep 4 waves on it.)
  {
    const int d = tid >> 1;
    const int p = tid & 1;
    const float* dwp = dtp_w + (size_t)(dir*128 + d) * 4;
    const float dw0 = dwp[0], dw1 = dwp[1], dw2 = dwp[2], dw3 = dwp[3];
    const float db = dtp_b[dir*128 + d];
    const float dpv = Dp[dir*128 + d];

    float Av[8];
    bool fast = true;
    #pragma unroll
    for (int j = 0; j < 8; ++j) {
      float a = -__expf(A_log[((size_t)(dir*128 + d))*16 + p*8 + j]);
      Av[j] = a;
      if (fabsf((-a) - (float)(p*8 + j + 1)) > 1e-3f) fast = false;
    }

    float h[8];
    #pragma unroll
    for (int j = 0; j < 8; ++j) h[j] = 0.f;

    // E = exp(-softplus(dr)) = 1/(1+exp(dr)): one exp + one rcp; E does not
    // wait on the log that produces dt.
    #define SCAN_LOAD                                                     \
      float4 q0 = *(const float4*)(smem + 18432 + l*272 + 256);           \
      float4 b0 = *(const float4*)(sBCf + l*36 + p*8);                    \
      float4 b1 = *(const float4*)(sBCf + l*36 + p*8 + 4);                \
      float4 c0 = *(const float4*)(sBCf + l*36 + 16 + p*8);               \
      float4 c1 = *(const float4*)(sBCf + l*36 + 16 + p*8 + 4);           \
      float Bv[8] = {b0.x,b0.y,b0.z,b0.w, b1.x,b1.y,b1.z,b1.w};           \
      float Cv[8] = {c0.x,c0.y,c0.z,c0.w, c1.x,c1.y,c1.z,c1.w};           \
      float dr = q0.x*dw0 + q0.y*dw1 + q0.z*dw2 + q0.w*dw3 + db;          \
      float te = __expf(dr);                                              \
      float dt = (dr > 20.f) ? dr : __logf(1.f + te);                     \
      float u = bf2f(sUC[l*136 + d]);                                     \
      float dtu = dt * u;

    if (fast) {
      for (int l = 0; l < 128; ++l) {
        SCAN_LOAD
        float E = fastrcp(1.f + te);
        float E2 = E*E, E4 = E2*E2, E8 = E4*E4;
        float e = p ? E8 : 1.f;
        float yp = 0.f;
        #pragma unroll
        for (int j = 0; j < 8; ++j) {
          e *= E;
          h[j] = h[j]*e + dtu*Bv[j];
          yp += h[j]*Cv[j];
        }
        float ysum = yp + __shfl_xor(yp, 1, 64);
        if (p == 0) sUC[l*136 + d] = f2bf(ysum + u*dpv);
      }
    } else {
      for (int l = 0; l < 128; ++l) {
        SCAN_LOAD
        float yp = 0.f;
        #pragma unroll
        for (int j = 0; j < 8; ++j) {
          float ej = __expf(dt*Av[j]);
          h[j] = h[j]*ej + dtu*Bv[j];
          yp += h[j]*Cv[j];
        }
        float ysum = yp + __shfl_xor(yp, 1, 64);
        if (p == 0) sUC[l*136 + d] = f2bf(ysum + u*dpv);
      }
    }
    #undef SCAN_LOAD
  }
  __syncthreads();

  // ---- phase 6: yf = y * silu(z) from registers; dir-dependent YF layout.
  //      dir 0/1: [n_all][l][d]; dir 2/3: transposed [dir][b*128+h][w][d].
  #pragma unroll
  for (int tt = 0; tt < 2; ++tt) {
    const int st = tt ? st1 : st0;
    size_t rowbase;
    if (dir < 2)       rowbase = ((size_t)n_all*128 + st)*128;
    else if (dir == 2) rowbase = ((size_t)(512 + b*128 + st)*128 + r)*128;
    else               rowbase = ((size_t)(768 + b*128 + (127-st))*128 + r)*128;
    #pragma unroll
    for (int k = 0; k < 8; ++k) {
      const int dz = 16*k + quad*4;
      uint2 yv = *(const uint2*)(sUC + st*136 + dz);
      float y0 = __uint_as_float(yv.x << 16);
      float y1 = __uint_as_float(yv.x & 0xffff0000u);
      float y2 = __uint_as_float(yv.y << 16);
      float y3 = __uint_as_float(yv.y & 0xffff0000u);
      unsigned int z01 = zpk[tt][k][0], z23 = zpk[tt][k][1];
      float z0 = __uint_as_float(z01 << 16);
      float z1 = __uint_as_float(z01 & 0xffff0000u);
      float z2 = __uint_as_float(z23 << 16);
      float z3 = __uint_as_float(z23 & 0xffff0000u);
      uint2 ov;
      ov.x = pk2bf(y0*z0, y1*z1);
      ov.y = pk2bf(y2*z2, y3*z3);
      *(uint2*)(YF + rowbase + dz) = ov;
    }
  }
}

// ---------------------------------------------------------------- K3 (MFMA fuse + LN)
__global__ __launch_bounds__(256, 2) void k3_fuse(
    const unsigned short* __restrict__ YF, const unsigned short* __restrict__ MT16,
    const float* __restrict__ fuse_b, const float* __restrict__ ln_g,
    const float* __restrict__ ln_b, float* __restrict__ out)
{
  __shared__ __align__(16) unsigned short sYB[64*520];   // 66,560 B

  const int tid = threadIdx.x;
  const int blk = blockIdx.x;             // 512
  const int b = blk >> 8;
  const int rr2 = blk & 255;
  const int h = rr2 >> 1;
  const int w0 = (rr2 & 1) * 64;

  for (int f = tid*8; f < 32768; f += 2048) {
    int dirg = f >> 13;
    int rem = f & 8191;
    int tok = rem >> 7;
    int dd = rem & 127;
    int X = (dirg == 1) ? (127 - w0 - tok) : (w0 + tok);
    size_t base = ((size_t)(dirg*256 + b*128 + h)*128 + X)*128 + dd;
    *(uint4*)(sYB + tok*520 + dirg*128 + dd) = *(const uint4*)(YF + base);
  }
  __syncthreads();

  const int wave = tid >> 6;
  const int lane = tid & 63;
  const int m16 = lane & 15;
  const int quad = lane >> 4;
  const int tok = wave*16 + m16;

  short8 bfr[16];
  #pragma unroll
  for (int jt = 0; jt < 16; ++jt)
    bfr[jt] = *(const short8*)(sYB + tok*520 + jt*32 + quad*8);

  float facc[4][4];
  #pragma unroll
  for (int mt = 0; mt < 4; ++mt) {
    f32x4 acc = {0.f, 0.f, 0.f, 0.f};
    #pragma unroll
    for (int jt = 0; jt < 16; ++jt) {
      short8 af = *(const short8*)(MT16 + (size_t)(mt*16 + m16)*512 + jt*32 + quad*8);
      acc = __builtin_amdgcn_mfma_f32_16x16x32_bf16(af, bfr[jt], acc, 0, 0, 0);
    }
    facc[mt][0] = acc[0]; facc[mt][1] = acc[1]; facc[mt][2] = acc[2]; facc[mt][3] = acc[3];
  }

  float fv[16];
  float s1 = 0.f, s2 = 0.f;
  #pragma unroll
  for (int mt = 0; mt < 4; ++mt)
    #pragma unroll
    for (int rr = 0; rr < 4; ++rr) {
      int o = mt*16 + quad*4 + rr;
      float v = facc[mt][rr] + fuse_b[o];
      fv[mt*4 + rr] = v;
      s1 += v; s2 += v*v;
    }
  s1 += __shfl_xor(s1, 16, 64); s1 += __shfl_xor(s1, 32, 64);
  s2 += __shfl_xor(s2, 16, 64); s2 += __shfl_xor(s2, 32, 64);
  float mu = s1 * (1.f/64.f);
  float var = s2 * (1.f/64.f) - mu*mu;
  float rs = rsqrtf(var + 1e-5f);

  #pragma unroll
  for (int mt = 0; mt < 4; ++mt)
    #pragma unroll
    for (int rr = 0; rr < 4; ++rr) {
      int o = mt*16 + quad*4 + rr;
      float v = (fv[mt*4 + rr] - mu) * rs * ln_g[o] + ln_b[o];
      out[((size_t)(b*64 + o)*128 + h)*128 + (w0 + tok)] = siluf(v);
    }
}

// ---------------------------------------------------------------- host
extern "C" void kernel_launch(void* const* d_in, const int* in_sizes, int n_in,
                              void* d_out, int out_size, void* d_ws, size_t ws_size,
                              hipStream_t stream) {
  const float* x      = (const float*)d_in[0];
  const float* in_w   = (const float*)d_in[1];
  const float* conv_w = (const float*)d_in[2];
  const float* conv_b = (const float*)d_in[3];
  const float* xp_w   = (const float*)d_in[4];
  const float* dtp_w  = (const float*)d_in[5];
  const float* dtp_b  = (const float*)d_in[6];
  const float* A_log  = (const float*)d_in[7];
  const float* Dp     = (const float*)d_in[8];
  const float* out_w  = (const float*)d_in[9];
  const float* fuse_w = (const float*)d_in[10];
  const float* fuse_b = (const float*)d_in[11];
  const float* ln_g   = (const float*)d_in[12];
  const float* ln_b   = (const float*)d_in[13];
  float* out = (float*)d_out;

  // ws layout (BYTES):
  char* ws = (char*)d_ws;
  unsigned short* YF   = (unsigned short*)(ws);              // 33,554,432 (yf, dir-layouts)
  unsigned short* MT16 = (unsigned short*)(ws + 33554432);   //     65,536
  unsigned short* W16  = (unsigned short*)(ws + 33619968);   //    131,072
  unsigned short* XW16 = (unsigned short*)(ws + 33751040);   //     49,152
  unsigned short* XH   = (unsigned short*)(ws + 33800192);   //  4,194,304 (xhwc16)
  unsigned short* XWt  = (unsigned short*)(ws + 37994496);   //  4,194,304 (xwhc16)
  // total 42,188,800 B

  k0_prep<<<dim3(420), dim3(256), 0, stream>>>(out_w, fuse_w, in_w, xp_w, x,
                                               MT16, W16, XW16, XH, XWt);
  k1_front<<<dim3(1024), dim3(256), 0, stream>>>(XH, XWt, W16, XW16, conv_w, conv_b,
                                                 dtp_w, dtp_b, A_log, Dp, YF);
  k3_fuse<<<dim3(512), dim3(256), 0, stream>>>(YF, MT16, fuse_b, ln_g, ln_b, out);
}